// Round 5
// baseline (67.310 us; speedup 1.0000x reference)
//
#include <hip/hip_runtime.h>

#define NUM_K 1024
#define DIM 256
#define HWDIM 1024
#define BETA 0.25f
#define NTOT 8388608  // 32*256*32*32
#define DIST_C 0.25f  // keeps dist = ||e||^2 + C - 2 x.e positive

typedef __attribute__((ext_vector_type(8))) short short8;
typedef __attribute__((ext_vector_type(4))) float fx4;
typedef unsigned short u16;
typedef unsigned int u32;

// d_ws (floats): [0] loss acc | [64..1088) enorm+C | [1088..132160) frag-ordered bf16 codebook
//                | [132160..164928) idx (int)
//   frag layout: [gc=code/16][s=0..7][lane=0..63][e=0..7]; code = gc*16+(lane&15),
//   dim = s*32+(lane>>4)*8+e  -> staging and ds_read are both perfectly linear.
#define WS_IDX_OFF 132160

__device__ __forceinline__ u16 f2bf(float f) {
    u32 b = __builtin_bit_cast(u32, f);
    return (u16)((b + 0x7FFFu + ((b >> 16) & 1u)) >> 16);  // RNE
}

// fused prep: blocks [0,128) build frag codebook; blocks [128,384) build enorm
__global__ void prep_kernel(const float* __restrict__ wgt, float* __restrict__ ws) {
    if (blockIdx.x < 128) {
        int g = blockIdx.x * 256 + threadIdx.x;       // 0..32767
        int lane = g & 63, s = (g >> 6) & 7, gc = g >> 9;
        int code = gc * 16 + (lane & 15);
        int d0 = s * 32 + (lane >> 4) * 8;
        const float* p = wgt + (size_t)code * DIM + d0;
        float4 a = *reinterpret_cast<const float4*>(p);
        float4 b = *reinterpret_cast<const float4*>(p + 4);
        u16* dst = reinterpret_cast<u16*>(ws + 1088) + (size_t)g * 8;
        ushort4 lo, hi;
        lo.x = f2bf(a.x); lo.y = f2bf(a.y); lo.z = f2bf(a.z); lo.w = f2bf(a.w);
        hi.x = f2bf(b.x); hi.y = f2bf(b.y); hi.z = f2bf(b.z); hi.w = f2bf(b.w);
        *reinterpret_cast<ushort4*>(dst) = lo;
        *reinterpret_cast<ushort4*>(dst + 4) = hi;
    } else {
        int wave = threadIdx.x >> 6, lane = threadIdx.x & 63;
        int k = (blockIdx.x - 128) * 4 + wave;
        if (blockIdx.x == 128 && threadIdx.x == 0) ws[0] = 0.f;
        const float4 v = *reinterpret_cast<const float4*>(wgt + (size_t)k * DIM + lane * 4);
        float s = v.x * v.x + v.y * v.y + v.z * v.z + v.w * v.w;
        #pragma unroll
        for (int off = 32; off > 0; off >>= 1) s += __shfl_down(s, off, 64);
        if (lane == 0) ws[64 + k] = s + DIST_C;
    }
}

__device__ __forceinline__ void gl2lds16(const void* g, void* l) {
    __builtin_amdgcn_global_load_lds(
        (const __attribute__((address_space(1))) u32*)g,
        (__attribute__((address_space(3))) u32*)l, 16, 0, 0);
}

// swizzled ushort index into xs[64][256]
__device__ __forceinline__ int xsw(int row, int d) {
    return (row * 256 + d) ^ (((row ^ (row >> 3)) & 7) << 3);
}

__launch_bounds__(256, 2)
__global__ void argmin_kernel(const float* __restrict__ in,
                              float* __restrict__ ws,
                              int* __restrict__ idx_out) {
    // LDS: [0,64K) per-wave B dbuf (wave w: [w*16K,+8K) and [+8K,+16K))
    //      [32K,64K) aliases xs (x-tile), dead after af-hoist
    //      [64K,68K) enorm ; [68K,69K) cand
    __shared__ __align__(16) unsigned char smem[70656];
    u16* xs = reinterpret_cast<u16*>(smem + 32768);
    float* eno = reinterpret_cast<float*>(smem + 65536);
    float (*cand)[64] = reinterpret_cast<float (*)[64]>(smem + 69632);
    const u16* ebf2 = reinterpret_cast<const u16*>(ws + 1088);

    const int tid = threadIdx.x;
    const int lane = tid & 63;
    const int wv = tid >> 6;
    const int tx = lane & 15;
    const int tz = lane >> 4;
    const int bid = blockIdx.x;
    const int bb = bid >> 4;
    const int hw0 = (bid & 15) << 6;
    const float* inb = in + (size_t)bb * (DIM * HWDIM) + hw0;

    // ---- stage enorm -> LDS ----
    reinterpret_cast<float4*>(eno)[tid] = reinterpret_cast<const float4*>(ws + 64)[tid];

    // ---- stage x: fp32 [d][hw] -> bf16 [row][d] LDS (swizzled); Sum x^2 on the fly ----
    float xsq = 0.f;
    {
        int hw4 = (tid & 15) << 2;
        int dp = tid >> 4;
        #pragma unroll
        for (int it = 0; it < 8; ++it) {
            int d = dp * 2 + it * 32;
            float4 v0 = *reinterpret_cast<const float4*>(inb + (size_t)d * HWDIM + hw4);
            float4 v1 = *reinterpret_cast<const float4*>(inb + (size_t)(d + 1) * HWDIM + hw4);
            xsq += v0.x * v0.x + v0.y * v0.y + v0.z * v0.z + v0.w * v0.w
                 + v1.x * v1.x + v1.y * v1.y + v1.z * v1.z + v1.w * v1.w;
            u32 p0 = (u32)f2bf(v0.x) | ((u32)f2bf(v1.x) << 16);
            u32 p1 = (u32)f2bf(v0.y) | ((u32)f2bf(v1.y) << 16);
            u32 p2 = (u32)f2bf(v0.z) | ((u32)f2bf(v1.z) << 16);
            u32 p3 = (u32)f2bf(v0.w) | ((u32)f2bf(v1.w) << 16);
            *reinterpret_cast<u32*>(&xs[xsw(hw4 + 0, d)]) = p0;
            *reinterpret_cast<u32*>(&xs[xsw(hw4 + 1, d)]) = p1;
            *reinterpret_cast<u32*>(&xs[xsw(hw4 + 2, d)]) = p2;
            *reinterpret_cast<u32*>(&xs[xsw(hw4 + 3, d)]) = p3;
        }
    }
    #pragma unroll
    for (int off = 32; off > 0; off >>= 1) xsq += __shfl_down(xsq, off, 64);
    if (lane == 0) atomicAdd(&ws[0], xsq);
    __syncthreads();

    // ---- hoist A fragments: row = rf*16+tx, k = s*32+tz*8+[0..7] ----
    short8 af[4][8];
    #pragma unroll
    for (int rf = 0; rf < 4; ++rf) {
        #pragma unroll
        for (int s = 0; s < 8; ++s)
            af[rf][s] = *reinterpret_cast<const short8*>(&xs[xsw(rf * 16 + tx, s * 32 + tz * 8)]);
    }
    __syncthreads();                 // all waves done reading xs (B bufs alias it)
    asm volatile("" ::: "memory");   // af must stay in regs: LDS below is overwritten

    // ---- main loop: per-wave LDS double-buffered B, no barriers ----
    u16* buf0 = reinterpret_cast<u16*>(smem + wv * 16384);
    u16* buf1 = buf0 + 4096;
    const unsigned char* gsrc = reinterpret_cast<const unsigned char*>(ebf2)
                                + (size_t)wv * 16 * 8192 + lane * 16;
    auto stage = [&](int ch, u16* buf) {
        const unsigned char* sp = gsrc + ch * 8192;
        unsigned char* dp = reinterpret_cast<unsigned char*>(buf);
        #pragma unroll
        for (int i = 0; i < 8; ++i)
            gl2lds16(sp + i * 1024, dp + i * 1024);
    };
    stage(0, buf0);
    stage(1, buf1);

    float minkey[16];
    #pragma unroll
    for (int q = 0; q < 16; ++q) minkey[q] = 1e30f;

    #pragma unroll
    for (int ch = 0; ch < 16; ++ch) {
        if (ch == 15) asm volatile("s_waitcnt vmcnt(0)" ::: "memory");
        else          asm volatile("s_waitcnt vmcnt(8)" ::: "memory");
        const u16* cb = (ch & 1) ? buf1 : buf0;
        short8 bf[8];
        #pragma unroll
        for (int s = 0; s < 8; ++s)
            bf[s] = *reinterpret_cast<const short8*>(cb + s * 512 + lane * 8);
        fx4 acc[4];
        const fx4 z = {0.f, 0.f, 0.f, 0.f};
        #pragma unroll
        for (int rf = 0; rf < 4; ++rf) acc[rf] = z;
        __builtin_amdgcn_s_setprio(1);
        #pragma unroll
        for (int s = 0; s < 8; ++s) {
            #pragma unroll
            for (int rf = 0; rf < 4; ++rf)
                acc[rf] = __builtin_amdgcn_mfma_f32_16x16x32_bf16(af[rf][s], bf[s], acc[rf], 0, 0, 0);
        }
        __builtin_amdgcn_s_setprio(0);
        if (ch < 14) stage(ch + 2, (ch & 1) ? buf1 : buf0);
        float en = eno[wv * 256 + ch * 16 + tx];
        const u32 codebase = (u32)(wv * 256 + ch * 16 + tx);
        #pragma unroll
        for (int rf = 0; rf < 4; ++rf) {
            #pragma unroll
            for (int r = 0; r < 4; ++r) {
                float d = fmaf(-2.f, acc[rf][r], en);
                u32 u = (__builtin_bit_cast(u32, d) & 0xFFFFFC00u) | codebase;
                int q = rf * 4 + r;
                minkey[q] = fminf(minkey[q], __builtin_bit_cast(float, u));
            }
        }
    }

    // ---- reduce over the 16 col-lanes ----
    #pragma unroll
    for (int q = 0; q < 16; ++q) {
        float v = minkey[q];
        #pragma unroll
        for (int off = 1; off < 16; off <<= 1)
            v = fminf(v, __shfl_xor(v, off, 64));
        minkey[q] = v;
    }
    if (tx == 0) {
        #pragma unroll
        for (int rf = 0; rf < 4; ++rf) {
            #pragma unroll
            for (int r = 0; r < 4; ++r)
                cand[wv][rf * 16 + tz * 4 + r] = minkey[rf * 4 + r];
        }
    }
    __syncthreads();
    if (tid < 64) {
        float bv = fminf(fminf(cand[0][tid], cand[1][tid]),
                         fminf(cand[2][tid], cand[3][tid]));
        u32 ub = __builtin_bit_cast(u32, bv);
        idx_out[bb * 1024 + hw0 + tid] = (int)(ub & 0x3FFu);
        // selected (truncated) distance, un-shifted
        float dsel = __builtin_bit_cast(float, ub & 0xFFFFFC00u) - DIST_C;
        #pragma unroll
        for (int off = 32; off > 0; off >>= 1) dsel += __shfl_down(dsel, off, 64);
        if (tid == 0) atomicAdd(&ws[0], dsel);
    }
}

__global__ void scatter_kernel(const float* __restrict__ wgt,
                               const int* __restrict__ idx,
                               float* __restrict__ out) {
    const int tid = threadIdx.x;
    const int bid = blockIdx.x;
    const int bb = bid >> 4;
    const int hw0 = (bid & 15) << 6;
    const int hw4 = (tid & 15) << 2;
    const int dq = tid >> 4;
    const int* ip = idx + bb * 1024 + hw0 + hw4;
    int k0 = ip[0], k1 = ip[1], k2 = ip[2], k3 = ip[3];
    const float* e0 = wgt + (size_t)k0 * DIM;
    const float* e1 = wgt + (size_t)k1 * DIM;
    const float* e2 = wgt + (size_t)k2 * DIM;
    const float* e3 = wgt + (size_t)k3 * DIM;
    float* outb = out + (size_t)bb * (DIM * HWDIM) + hw0;
    #pragma unroll
    for (int m = 0; m < 4; ++m) {
        int d0 = dq * 16 + m * 4;
        float4 r0 = *reinterpret_cast<const float4*>(e0 + d0);
        float4 r1 = *reinterpret_cast<const float4*>(e1 + d0);
        float4 r2 = *reinterpret_cast<const float4*>(e2 + d0);
        float4 r3 = *reinterpret_cast<const float4*>(e3 + d0);
        float er0[4] = {r0.x, r0.y, r0.z, r0.w};
        float er1[4] = {r1.x, r1.y, r1.z, r1.w};
        float er2[4] = {r2.x, r2.y, r2.z, r2.w};
        float er3[4] = {r3.x, r3.y, r3.z, r3.w};
        #pragma unroll
        for (int qd = 0; qd < 4; ++qd) {
            float4 ev = {er0[qd], er1[qd], er2[qd], er3[qd]};
            *reinterpret_cast<float4*>(outb + (size_t)(d0 + qd) * HWDIM + hw4) = ev;
        }
    }
}

__global__ void loss_kernel(const float* __restrict__ ws, float* __restrict__ out_loss) {
    out_loss[0] = (1.f + BETA) * ws[0] / (float)NTOT;
}

extern "C" void kernel_launch(void* const* d_in, const int* in_sizes, int n_in,
                              void* d_out, int out_size, void* d_ws, size_t ws_size,
                              hipStream_t stream) {
    const float* enc = (const float*)d_in[0];
    const float* wgt = (const float*)d_in[1];
    float* out = (float*)d_out;
    float* ws = (float*)d_ws;
    int* idx = reinterpret_cast<int*>(ws + WS_IDX_OFF);

    prep_kernel<<<384, 256, 0, stream>>>(wgt, ws);
    argmin_kernel<<<512, 256, 0, stream>>>(enc, ws, idx);
    scatter_kernel<<<512, 256, 0, stream>>>(wgt, idx, out);
    loss_kernel<<<1, 1, 0, stream>>>(ws, out + NTOT);
}